// Round 2
// baseline (468.394 us; speedup 1.0000x reference)
//
#include <hip/hip_runtime.h>

#define SEQ 640
#define BATCH 40
#define D_IN 8
#define D_TRAJ 32
#define D_LSTM 64
#define G4 256        // 4 * D_LSTM
#define NH 4
#define DH 48
#define EMB 192

typedef float v2f __attribute__((ext_vector_type(2)));
typedef float v4f __attribute__((ext_vector_type(4)));
typedef _Float16 h2t __attribute__((ext_vector_type(2)));

__device__ __forceinline__ float sigmoid_f(float x) {
    float e = __expf(-x);
    return __builtin_amdgcn_rcpf(1.f + e);
}
__device__ __forceinline__ float tanh_f(float x) {
    float e = __expf(2.f * x);
    return 1.f - 2.f * __builtin_amdgcn_rcpf(e + 1.f);
}

// ---------------------------------------------------------------------------
// Kernel 1: trajectory embed (ELU) + input-side LSTM gate precompute.
// gates_x layout [b][g][t][j]: wave g of k_lstm reads one coalesced dword
// per lane per step.
// grid: 640 blocks (t), 256 threads.
// ---------------------------------------------------------------------------
__global__ void __launch_bounds__(256) k_embed(
    const float* __restrict__ hist, const float* __restrict__ W1,
    const float* __restrict__ b1, const float* __restrict__ W_ih,
    const float* __restrict__ b_ih, const float* __restrict__ b_hh,
    float* __restrict__ gates_x)
{
    __shared__ float sh_hist[BATCH * D_IN];     // 320
    __shared__ float sh_traj[BATCH * D_TRAJ];   // 1280
    const int t = blockIdx.x, tid = threadIdx.x;

    for (int i = tid; i < BATCH * D_IN; i += 256)
        sh_hist[i] = hist[t * BATCH * D_IN + i];
    __syncthreads();

    for (int idx = tid; idx < BATCH * D_TRAJ; idx += 256) {
        int b = idx >> 5, h = idx & 31;
        float acc = b1[h];
        #pragma unroll
        for (int f = 0; f < D_IN; ++f)
            acc += sh_hist[b * D_IN + f] * W1[h * D_IN + f];
        sh_traj[idx] = acc > 0.f ? acc : (__expf(acc) - 1.f);   // ELU
    }
    __syncthreads();

    float w[D_TRAJ];
    {
        const v4f* wv = (const v4f*)(W_ih + tid * D_TRAJ);
        #pragma unroll
        for (int u = 0; u < 8; ++u) {
            v4f x = wv[u];
            w[4*u] = x.x; w[4*u+1] = x.y; w[4*u+2] = x.z; w[4*u+3] = x.w;
        }
    }
    const float bias = b_ih[tid] + b_hh[tid];
    const int j = tid & 63, g = tid >> 6;       // unit, gate-type

    for (int b = 0; b < BATCH; ++b) {
        float acc = bias;
        #pragma unroll
        for (int h = 0; h < D_TRAJ; ++h)
            acc += sh_traj[b * D_TRAJ + h] * w[h];
        // [b][g][t][j] — coalesced per-wave per-step read in k_lstm
        gates_x[(((size_t)b * 4 + g) * SEQ + t) * 64 + j] = acc;
    }
}

// ---------------------------------------------------------------------------
// Kernel 2: LSTM recurrence — gate-parallel across 4 waves.
// R1 post-mortem: 862 cy/step; ~250 cy of that is the 32 v_readlane -> fdot2
// SGPR path (VALU-writes-SGPR -> VALU-reads-SGPR hazard wait-states, present
// in BOTH the 980cy 1-wave and 862cy 4-wave versions). This version replaces
// the readlane broadcast with ds_bpermute_b32 (VGPR->VGPR lane crossbar, no
// SGPR hazard, pipelined through lgkmcnt). Indices (byte addr 8*m of the
// even lane of pair m) are loop-invariant and hoisted to VGPRs. Everything
// else is bit-identical to R1 (same f16 pairs, same fdot2 order, same
// exchange) so this isolates the hazard hypothesis.
// grid: 40 blocks x 256 threads.
// ---------------------------------------------------------------------------
__global__ void __launch_bounds__(256, 1) k_lstm(
    const float* __restrict__ gates_x, const float* __restrict__ W_hh,
    float* __restrict__ seq_out)
{
    const int b = blockIdx.x;
    const int tid = threadIdx.x;
    const int g = tid >> 6;      // wave id == gate (i, f, g, o)
    const int j = tid & 63;      // unit

    __shared__ float sg[2][4][64];   // double-buffered raw gate sums

    // f16-packed recurrent weight row for (gate g, unit j)
    h2t w2[32];
    {
        const float* Wrow = W_hh + (g * 64 + j) * D_LSTM;
        #pragma unroll
        for (int m = 0; m < 32; ++m)
            w2[m] = (h2t){(_Float16)Wrow[2*m], (_Float16)Wrow[2*m+1]};
    }

    // loop-invariant bpermute byte-indices: pair m lives in lane 2m
    int bidx[32];
    #pragma unroll
    for (int m = 0; m < 32; ++m) bidx[m] = 8 * m;

    // x-side gate stream: [b][g][t][j], one dword per lane per step
    const float* gx = gates_x + (((size_t)b * 4 + g) * SEQ) * 64 + j;
    float gq0 = gx[0 * 64];
    float gq1 = gx[1 * 64];
    float gq2 = gx[2 * 64];
    float gq3 = gx[3 * 64];

    float h = 0.f, c = 0.f;
    float hpf = 0.f;                 // packed f16 pair (h_{2m}, h_{2m+1})
    const bool odd = (j & 1);

    auto step = [&](float& gq, int t) {
        const int hbits = __builtin_bit_cast(int, hpf);

        // broadcast packed h pairs via lane crossbar (VGPR->VGPR, no SGPR
        // hazard); issue all 32 up front so lgkmcnt waits pipeline.
        int hp[32];
        #pragma unroll
        for (int m = 0; m < 32; ++m)
            hp[m] = __builtin_amdgcn_ds_bpermute(bidx[m], hbits);

        // gate-g matvec: 4 independent chains of 8 fdot2
        float a0 = gq, a1 = 0.f, a2 = 0.f, a3 = 0.f;
        #pragma unroll
        for (int m = 0; m < 8; ++m)
            a0 = __builtin_amdgcn_fdot2(w2[m],
                    __builtin_bit_cast(h2t, hp[m]), a0, false);
        #pragma unroll
        for (int m = 8; m < 16; ++m)
            a1 = __builtin_amdgcn_fdot2(w2[m],
                    __builtin_bit_cast(h2t, hp[m]), a1, false);
        #pragma unroll
        for (int m = 16; m < 24; ++m)
            a2 = __builtin_amdgcn_fdot2(w2[m],
                    __builtin_bit_cast(h2t, hp[m]), a2, false);
        #pragma unroll
        for (int m = 24; m < 32; ++m)
            a3 = __builtin_amdgcn_fdot2(w2[m],
                    __builtin_bit_cast(h2t, hp[m]), a3, false);
        float a = (a0 + a1) + (a2 + a3);

        // exchange gates (conflict-free: wave g writes contiguous row g)
        const int buf = t & 1;
        sg[buf][g][j] = a;
        __syncthreads();
        float ai = sg[buf][0][j];
        float af = sg[buf][1][j];
        float ag = sg[buf][2][j];
        float ao = sg[buf][3][j];

        // redundant identical (c,h) update in every wave
        c = sigmoid_f(af) * c + sigmoid_f(ai) * tanh_f(ag);
        h = sigmoid_f(ao) * tanh_f(c);
        if (g == 0)
            seq_out[(size_t)(t * BATCH + b) * D_LSTM + j] = h;

        // pack (h_2m, h_2m+1) as f16 pair for next step's crossbar broadcast
        int own = (int)__builtin_bit_cast(unsigned short, (_Float16)h);
        int nb  = __builtin_amdgcn_update_dpp(0, own, 0xB1, 0xF, 0xF, true);
        int pk  = odd ? (nb | (own << 16)) : (own | (nb << 16));
        hpf = __builtin_bit_cast(float, pk);

        // prefetch x-gate 4 steps ahead
        int tp = t + 4; if (tp > SEQ - 1) tp = SEQ - 1;
        gq = gx[(size_t)tp * 64];
    };

    for (int t = 0; t < SEQ; t += 4) {
        step(gq0, t + 0);
        step(gq1, t + 1);
        step(gq2, t + 2);
        step(gq3, t + 3);
    }
}

// ---------------------------------------------------------------------------
// Kernel 3: attention, per-(head, t) — occupancy rebuild, f32 projection.
// (unchanged, R14/R17-proven precision boundary)
// grid: dim3(NH, SEQ), 256 threads.
// ---------------------------------------------------------------------------
#define SAS 68     // f32 stride of sA rows (16B-aligned)
#define SKVS 152   // f16 stride of qkv rows (304B, 16B-aligned): q@0,k@48,v@96
#define SSS 44     // f32 stride for score rows
__global__ void __launch_bounds__(256) k_attn(
    const float* __restrict__ seq,
    const float* __restrict__ Wq, const float* __restrict__ bq,
    const float* __restrict__ Wk, const float* __restrict__ bk,
    const float* __restrict__ Wv, const float* __restrict__ bv,
    float* __restrict__ o_buf)
{
    const int h = blockIdx.x, t = blockIdx.y, tid = threadIdx.x;
    __shared__ float sA[BATCH * SAS];          // 10.9 KB (f32)
    __shared__ _Float16 skqv[BATCH * SKVS];    // 12.2 KB
    __shared__ float ss[BATCH * SSS];          // 7.0 KB

    // ---- stage seq_t as f32 ----
    for (int i = tid; i < BATCH * D_LSTM; i += 256)
        sA[(i >> 6) * SAS + (i & 63)] = seq[(size_t)t * BATCH * D_LSTM + i];
    __syncthreads();

    // ---- projection: thread c (<144) owns one channel; f32 math ----
    if (tid < 144) {
        int m = tid / 48, d = tid - m * 48;
        const float* W = (m == 0) ? Wq : (m == 1) ? Wk : Wv;
        const float* B = (m == 0) ? bq : (m == 1) ? bk : bv;
        const float* wrow = W + (h * DH + d) * D_LSTM;
        float wreg[D_LSTM];
        {
            const v4f* wv = (const v4f*)wrow;   // coalesced f32 loads
            #pragma unroll
            for (int u = 0; u < 16; ++u) {
                v4f x = wv[u];
                wreg[4*u] = x.x; wreg[4*u+1] = x.y;
                wreg[4*u+2] = x.z; wreg[4*u+3] = x.w;
            }
        }
        const float bias = B[h * DH + d];

        for (int a = 0; a < BATCH; ++a) {
            const v4f* ap = (const v4f*)&sA[a * SAS];   // broadcast b128 reads
            float acc = bias;
            #pragma unroll
            for (int u = 0; u < 16; ++u) {
                v4f av = ap[u];
                acc += av.x * wreg[4*u]   + av.y * wreg[4*u+1]
                     + av.z * wreg[4*u+2] + av.w * wreg[4*u+3];
            }
            skqv[a * SKVS + tid] = (_Float16)acc;       // f16 store (proven)
        }
    }
    __syncthreads();

    // ---- scores = q k^T / 8 (f16 dots, R14-proven) ----
    for (int idx = tid; idx < BATCH * BATCH; idx += 256) {
        int i = idx / BATCH, jj = idx % BATCH;
        const v4f* qp = (const v4f*)&skqv[i * SKVS];        // q @ 0
        const v4f* kp = (const v4f*)&skqv[jj * SKVS + 48];  // k @ 48 (96B)
        float acc = 0.f;
        #pragma unroll
        for (int u = 0; u < 6; ++u) {
            v4f qv = qp[u], kv = kp[u];
            acc = __builtin_amdgcn_fdot2(__builtin_bit_cast(h2t, qv.x),
                    __builtin_bit_cast(h2t, kv.x), acc, false);
            acc = __builtin_amdgcn_fdot2(__builtin_bit_cast(h2t, qv.y),
                    __builtin_bit_cast(h2t, kv.y), acc, false);
            acc = __builtin_amdgcn_fdot2(__builtin_bit_cast(h2t, qv.z),
                    __builtin_bit_cast(h2t, kv.z), acc, false);
            acc = __builtin_amdgcn_fdot2(__builtin_bit_cast(h2t, qv.w),
                    __builtin_bit_cast(h2t, kv.w), acc, false);
        }
        ss[i * SSS + jj] = acc * 0.125f;
    }
    __syncthreads();

    // ---- row softmax (row in registers; R14-validated) ----
    if (tid < BATCH) {
        v4f* rp = (v4f*)&ss[tid * SSS];
        v4f r[10];
        #pragma unroll
        for (int u = 0; u < 10; ++u) r[u] = rp[u];
        float m = -1e30f;
        #pragma unroll
        for (int u = 0; u < 10; ++u)
            m = fmaxf(m, fmaxf(fmaxf(r[u].x, r[u].y), fmaxf(r[u].z, r[u].w)));
        float s = 0.f;
        #pragma unroll
        for (int u = 0; u < 10; ++u) {
            r[u].x = __expf(r[u].x - m); s += r[u].x;
            r[u].y = __expf(r[u].y - m); s += r[u].y;
            r[u].z = __expf(r[u].z - m); s += r[u].z;
            r[u].w = __expf(r[u].w - m); s += r[u].w;
        }
        float inv = __builtin_amdgcn_rcpf(s);
        #pragma unroll
        for (int u = 0; u < 10; ++u) {
            r[u].x *= inv; r[u].y *= inv; r[u].z *= inv; r[u].w *= inv;
            rp[u] = r[u];
        }
    }
    __syncthreads();

    // ---- AV: slot = (bi, 8 d's); 240 slots (R14-validated) ----
    if (tid < 240) {
        int bi = tid / 6, dg = tid % 6, d0 = dg * 8;
        const v4f* sp = (const v4f*)&ss[bi * SSS];
        v4f sr[10];
        #pragma unroll
        for (int u = 0; u < 10; ++u) sr[u] = sp[u];
        float acc[8];
        #pragma unroll
        for (int d = 0; d < 8; ++d) acc[d] = 0.f;
        for (int jj = 0; jj < 40; ++jj) {
            float a = ((const float*)&sr[jj >> 2])[jj & 3];
            v4f vv = *(const v4f*)&skqv[jj * SKVS + 96 + d0];  // v @ 96 (192B)
            #pragma unroll
            for (int w = 0; w < 4; ++w) {
                h2t pr = __builtin_bit_cast(h2t, ((const float*)&vv)[w]);
                acc[2 * w]     += a * (float)pr[0];
                acc[2 * w + 1] += a * (float)pr[1];
            }
        }
        float* ob = &o_buf[((size_t)t * BATCH + bi) * EMB + h * DH + d0];
        *(v4f*)&ob[0] = (v4f){acc[0], acc[1], acc[2], acc[3]};
        *(v4f*)&ob[4] = (v4f){acc[4], acc[5], acc[6], acc[7]};
    }
}

// ---------------------------------------------------------------------------
// Kernel 4: GLU + residual + LayerNorm, per t — R13-PROVEN VERBATIM.
// grid: 640 blocks, 256 threads.
// ---------------------------------------------------------------------------
__global__ void __launch_bounds__(256) k_glu_ln(
    const float* __restrict__ seq, const float* __restrict__ obuf,
    const float* __restrict__ Wa, const float* __restrict__ ba,
    const float* __restrict__ Wg, const float* __restrict__ bg,
    const float* __restrict__ gamma, const float* __restrict__ beta,
    float* __restrict__ out)
{
    const int t = blockIdx.x, tid = threadIdx.x;
    __shared__ float so[BATCH * 193];       // o_t padded (192 -> 193)
    __shared__ float sy[BATCH * 65];        // y padded
    __shared__ float sseq[BATCH * D_LSTM];

    const float* ot = obuf + (size_t)t * BATCH * EMB;
    for (int i = tid; i < BATCH * EMB; i += 256)
        so[(i / EMB) * 193 + (i % EMB)] = ot[i];
    for (int i = tid; i < BATCH * D_LSTM; i += 256)
        sseq[i] = seq[(size_t)t * BATCH * D_LSTM + i];
    __syncthreads();

    const int j = tid >> 2, bgr = tid & 3;
    float acc_a[10], acc_g[10];
    #pragma unroll
    for (int bb = 0; bb < 10; ++bb) { acc_a[bb] = ba[j]; acc_g[bb] = bg[j]; }

    const float* wa = Wa + j * EMB;
    const float* wg = Wg + j * EMB;
    for (int p = 0; p < EMB; ++p) {
        float a = wa[p], g = wg[p];
        #pragma unroll
        for (int bb = 0; bb < 10; ++bb) {
            float o = so[(bgr + 4 * bb) * 193 + p];
            acc_a[bb] += o * a;
            acc_g[bb] += o * g;
        }
    }
    #pragma unroll
    for (int bb = 0; bb < 10; ++bb) {
        int b = bgr + 4 * bb;
        float tv = acc_a[bb] * sigmoid_f(acc_g[bb]);
        sy[b * 65 + j] = sseq[b * D_LSTM + j] + tv;
    }
    __syncthreads();

    const int w = tid >> 6, lane = tid & 63;
    const float gm = gamma[lane], bt = beta[lane];
    for (int rr = 0; rr < 10; ++rr) {
        int b = w + 4 * rr;
        float y = sy[b * 65 + lane];
        float s1 = y, s2 = y * y;
        #pragma unroll
        for (int m = 1; m < 64; m <<= 1) {
            s1 += __shfl_xor(s1, m, 64);
            s2 += __shfl_xor(s2, m, 64);
        }
        float mu  = s1 * (1.f / 64.f);
        float var = s2 * (1.f / 64.f) - mu * mu;
        float inv = rsqrtf(var + 1e-5f);
        out[(size_t)t * BATCH * D_LSTM + b * D_LSTM + lane] =
            (y - mu) * inv * gm + bt;
    }
}

// ---------------------------------------------------------------------------
extern "C" void kernel_launch(void* const* d_in, const int* in_sizes, int n_in,
                              void* d_out, int out_size, void* d_ws, size_t ws_size,
                              hipStream_t stream)
{
    const float* hist = (const float*)d_in[0];
    // d_in[1] adj: unused (use_spatial=False)
    const float* W1   = (const float*)d_in[2];
    const float* b1   = (const float*)d_in[3];
    const float* W_ih = (const float*)d_in[4];
    const float* W_hh = (const float*)d_in[5];
    const float* b_ih = (const float*)d_in[6];
    const float* b_hh = (const float*)d_in[7];
    const float* Wq   = (const float*)d_in[8];
    const float* bq   = (const float*)d_in[9];
    const float* Wk   = (const float*)d_in[10];
    const float* bk   = (const float*)d_in[11];
    const float* Wv   = (const float*)d_in[12];
    const float* bv   = (const float*)d_in[13];
    const float* Wa   = (const float*)d_in[14];
    const float* ba   = (const float*)d_in[15];
    const float* Wg   = (const float*)d_in[16];
    const float* bg   = (const float*)d_in[17];
    const float* gamma = (const float*)d_in[18];
    const float* beta  = (const float*)d_in[19];
    float* out = (float*)d_out;

    float* ws = (float*)d_ws;
    float* gates_x = ws;                                   // 640*40*256 f
    float* seq     = ws + 6553600;                         // 640*40*64 f
    float* obuf    = ws + 6553600 + 1638400;               // 640*40*192 f

    hipLaunchKernelGGL(k_embed, dim3(SEQ), dim3(256), 0, stream,
                       hist, W1, b1, W_ih, b_ih, b_hh, gates_x);
    hipLaunchKernelGGL(k_lstm, dim3(BATCH), dim3(256), 0, stream,
                       gates_x, W_hh, seq);
    hipLaunchKernelGGL(k_attn, dim3(NH, SEQ), dim3(256), 0, stream,
                       seq, Wq, bq, Wk, bk, Wv, bv, obuf);
    hipLaunchKernelGGL(k_glu_ln, dim3(SEQ), dim3(256), 0, stream,
                       seq, obuf, Wa, ba, Wg, bg, gamma, beta, out);
}

// Round 3
// 468.095 us; speedup vs baseline: 1.0006x; 1.0006x over previous
//
#include <hip/hip_runtime.h>

#define SEQ 640
#define BATCH 40
#define D_IN 8
#define D_TRAJ 32
#define D_LSTM 64
#define G4 256        // 4 * D_LSTM
#define NH 4
#define DH 48
#define EMB 192

typedef float v2f __attribute__((ext_vector_type(2)));
typedef float v4f __attribute__((ext_vector_type(4)));
typedef _Float16 h2t __attribute__((ext_vector_type(2)));

__device__ __forceinline__ float sigmoid_f(float x) {
    float e = __expf(-x);
    return __builtin_amdgcn_rcpf(1.f + e);
}
__device__ __forceinline__ float tanh_f(float x) {
    float e = __expf(2.f * x);
    return 1.f - 2.f * __builtin_amdgcn_rcpf(e + 1.f);
}

// ---------------------------------------------------------------------------
// Kernel 1: trajectory embed (ELU) + input-side LSTM gate precompute.
// gates_x layout [b][g][t][j]: wave g of k_lstm reads one coalesced dword
// per lane per step.
// grid: 640 blocks (t), 256 threads.
// ---------------------------------------------------------------------------
__global__ void __launch_bounds__(256) k_embed(
    const float* __restrict__ hist, const float* __restrict__ W1,
    const float* __restrict__ b1, const float* __restrict__ W_ih,
    const float* __restrict__ b_ih, const float* __restrict__ b_hh,
    float* __restrict__ gates_x)
{
    __shared__ float sh_hist[BATCH * D_IN];     // 320
    __shared__ float sh_traj[BATCH * D_TRAJ];   // 1280
    const int t = blockIdx.x, tid = threadIdx.x;

    for (int i = tid; i < BATCH * D_IN; i += 256)
        sh_hist[i] = hist[t * BATCH * D_IN + i];
    __syncthreads();

    for (int idx = tid; idx < BATCH * D_TRAJ; idx += 256) {
        int b = idx >> 5, h = idx & 31;
        float acc = b1[h];
        #pragma unroll
        for (int f = 0; f < D_IN; ++f)
            acc += sh_hist[b * D_IN + f] * W1[h * D_IN + f];
        sh_traj[idx] = acc > 0.f ? acc : (__expf(acc) - 1.f);   // ELU
    }
    __syncthreads();

    float w[D_TRAJ];
    {
        const v4f* wv = (const v4f*)(W_ih + tid * D_TRAJ);
        #pragma unroll
        for (int u = 0; u < 8; ++u) {
            v4f x = wv[u];
            w[4*u] = x.x; w[4*u+1] = x.y; w[4*u+2] = x.z; w[4*u+3] = x.w;
        }
    }
    const float bias = b_ih[tid] + b_hh[tid];
    const int j = tid & 63, g = tid >> 6;       // unit, gate-type

    for (int b = 0; b < BATCH; ++b) {
        float acc = bias;
        #pragma unroll
        for (int h = 0; h < D_TRAJ; ++h)
            acc += sh_traj[b * D_TRAJ + h] * w[h];
        // [b][g][t][j] — coalesced per-wave per-step read in k_lstm
        gates_x[(((size_t)b * 4 + g) * SEQ + t) * 64 + j] = acc;
    }
}

// ---------------------------------------------------------------------------
// Kernel 2: LSTM recurrence — gate-parallel across 4 waves.
// R2 post-mortem: bpermute == readlane (236 vs 230 us) -> hazard theory
// falsified. The shared cost in R1/R2: __syncthreads() lowers to
// s_waitcnt vmcnt(0) lgkmcnt(0) + s_barrier, so EVERY step drains the
// in-flight gates_x prefetch (HBM/L2 latency 300-900cy) and the seq_out
// store at the barrier. This version: raw s_barrier with lgkmcnt(0)-only
// drain (inline asm + builtin barrier), leaving the prefetch load and the
// store in flight across the barrier (T4's counted-vmcnt principle; the
// compiler still inserts its own vmcnt wait before gq's USE, 4 steps
// later). Exchange math is bit-identical to R2.
// Correctness: lgkmcnt(0) before barrier => each wave's gate write is
// complete when it arrives => visible to all after barrier. Double buffer
// prevents WAR across steps. "memory" clobbers fence the LDS ops.
// grid: 40 blocks x 256 threads.
// ---------------------------------------------------------------------------
__global__ void __launch_bounds__(256, 1) k_lstm(
    const float* __restrict__ gates_x, const float* __restrict__ W_hh,
    float* __restrict__ seq_out)
{
    const int b = blockIdx.x;
    const int tid = threadIdx.x;
    const int g = tid >> 6;      // wave id == gate (i, f, g, o)
    const int j = tid & 63;      // unit

    __shared__ float sg[2][4][64];   // double-buffered raw gate sums

    // f16-packed recurrent weight row for (gate g, unit j)
    h2t w2[32];
    {
        const float* Wrow = W_hh + (g * 64 + j) * D_LSTM;
        #pragma unroll
        for (int m = 0; m < 32; ++m)
            w2[m] = (h2t){(_Float16)Wrow[2*m], (_Float16)Wrow[2*m+1]};
    }

    // loop-invariant bpermute byte-indices: pair m lives in lane 2m
    int bidx[32];
    #pragma unroll
    for (int m = 0; m < 32; ++m) bidx[m] = 8 * m;

    // x-side gate stream: [b][g][t][j], one dword per lane per step
    const float* gx = gates_x + (((size_t)b * 4 + g) * SEQ) * 64 + j;
    float gq0 = gx[0 * 64];
    float gq1 = gx[1 * 64];
    float gq2 = gx[2 * 64];
    float gq3 = gx[3 * 64];

    float h = 0.f, c = 0.f;
    float hpf = 0.f;                 // packed f16 pair (h_{2m}, h_{2m+1})
    const bool odd = (j & 1);

    auto step = [&](float& gq, int t) {
        const int hbits = __builtin_bit_cast(int, hpf);

        // broadcast packed h pairs via lane crossbar (VGPR->VGPR)
        int hp[32];
        #pragma unroll
        for (int m = 0; m < 32; ++m)
            hp[m] = __builtin_amdgcn_ds_bpermute(bidx[m], hbits);

        // gate-g matvec: 4 independent chains of 8 fdot2
        float a0 = gq, a1 = 0.f, a2 = 0.f, a3 = 0.f;
        #pragma unroll
        for (int m = 0; m < 8; ++m)
            a0 = __builtin_amdgcn_fdot2(w2[m],
                    __builtin_bit_cast(h2t, hp[m]), a0, false);
        #pragma unroll
        for (int m = 8; m < 16; ++m)
            a1 = __builtin_amdgcn_fdot2(w2[m],
                    __builtin_bit_cast(h2t, hp[m]), a1, false);
        #pragma unroll
        for (int m = 16; m < 24; ++m)
            a2 = __builtin_amdgcn_fdot2(w2[m],
                    __builtin_bit_cast(h2t, hp[m]), a2, false);
        #pragma unroll
        for (int m = 24; m < 32; ++m)
            a3 = __builtin_amdgcn_fdot2(w2[m],
                    __builtin_bit_cast(h2t, hp[m]), a3, false);
        float a = (a0 + a1) + (a2 + a3);

        // exchange gates via LDS with an LDS-ONLY barrier drain:
        // raw s_barrier + lgkmcnt(0) keeps the gates_x prefetch and the
        // seq_out store (vmcnt ops) in flight across the barrier.
        const int buf = t & 1;
        sg[buf][g][j] = a;
        asm volatile("s_waitcnt lgkmcnt(0)" ::: "memory");
        __builtin_amdgcn_s_barrier();
        asm volatile("" ::: "memory");
        float ai = sg[buf][0][j];
        float af = sg[buf][1][j];
        float ag = sg[buf][2][j];
        float ao = sg[buf][3][j];

        // redundant identical (c,h) update in every wave
        c = sigmoid_f(af) * c + sigmoid_f(ai) * tanh_f(ag);
        h = sigmoid_f(ao) * tanh_f(c);
        if (g == 0)
            seq_out[(size_t)(t * BATCH + b) * D_LSTM + j] = h;

        // pack (h_2m, h_2m+1) as f16 pair for next step's crossbar broadcast
        int own = (int)__builtin_bit_cast(unsigned short, (_Float16)h);
        int nb  = __builtin_amdgcn_update_dpp(0, own, 0xB1, 0xF, 0xF, true);
        int pk  = odd ? (nb | (own << 16)) : (own | (nb << 16));
        hpf = __builtin_bit_cast(float, pk);

        // prefetch x-gate 4 steps ahead (stays in flight across barriers)
        int tp = t + 4; if (tp > SEQ - 1) tp = SEQ - 1;
        gq = gx[(size_t)tp * 64];
    };

    for (int t = 0; t < SEQ; t += 4) {
        step(gq0, t + 0);
        step(gq1, t + 1);
        step(gq2, t + 2);
        step(gq3, t + 3);
    }
}

// ---------------------------------------------------------------------------
// Kernel 3: attention, per-(head, t) — occupancy rebuild, f32 projection.
// (unchanged, R14/R17-proven precision boundary)
// grid: dim3(NH, SEQ), 256 threads.
// ---------------------------------------------------------------------------
#define SAS 68     // f32 stride of sA rows (16B-aligned)
#define SKVS 152   // f16 stride of qkv rows (304B, 16B-aligned): q@0,k@48,v@96
#define SSS 44     // f32 stride for score rows
__global__ void __launch_bounds__(256) k_attn(
    const float* __restrict__ seq,
    const float* __restrict__ Wq, const float* __restrict__ bq,
    const float* __restrict__ Wk, const float* __restrict__ bk,
    const float* __restrict__ Wv, const float* __restrict__ bv,
    float* __restrict__ o_buf)
{
    const int h = blockIdx.x, t = blockIdx.y, tid = threadIdx.x;
    __shared__ float sA[BATCH * SAS];          // 10.9 KB (f32)
    __shared__ _Float16 skqv[BATCH * SKVS];    // 12.2 KB
    __shared__ float ss[BATCH * SSS];          // 7.0 KB

    // ---- stage seq_t as f32 ----
    for (int i = tid; i < BATCH * D_LSTM; i += 256)
        sA[(i >> 6) * SAS + (i & 63)] = seq[(size_t)t * BATCH * D_LSTM + i];
    __syncthreads();

    // ---- projection: thread c (<144) owns one channel; f32 math ----
    if (tid < 144) {
        int m = tid / 48, d = tid - m * 48;
        const float* W = (m == 0) ? Wq : (m == 1) ? Wk : Wv;
        const float* B = (m == 0) ? bq : (m == 1) ? bk : bv;
        const float* wrow = W + (h * DH + d) * D_LSTM;
        float wreg[D_LSTM];
        {
            const v4f* wv = (const v4f*)wrow;   // coalesced f32 loads
            #pragma unroll
            for (int u = 0; u < 16; ++u) {
                v4f x = wv[u];
                wreg[4*u] = x.x; wreg[4*u+1] = x.y;
                wreg[4*u+2] = x.z; wreg[4*u+3] = x.w;
            }
        }
        const float bias = B[h * DH + d];

        for (int a = 0; a < BATCH; ++a) {
            const v4f* ap = (const v4f*)&sA[a * SAS];   // broadcast b128 reads
            float acc = bias;
            #pragma unroll
            for (int u = 0; u < 16; ++u) {
                v4f av = ap[u];
                acc += av.x * wreg[4*u]   + av.y * wreg[4*u+1]
                     + av.z * wreg[4*u+2] + av.w * wreg[4*u+3];
            }
            skqv[a * SKVS + tid] = (_Float16)acc;       // f16 store (proven)
        }
    }
    __syncthreads();

    // ---- scores = q k^T / 8 (f16 dots, R14-proven) ----
    for (int idx = tid; idx < BATCH * BATCH; idx += 256) {
        int i = idx / BATCH, jj = idx % BATCH;
        const v4f* qp = (const v4f*)&skqv[i * SKVS];        // q @ 0
        const v4f* kp = (const v4f*)&skqv[jj * SKVS + 48];  // k @ 48 (96B)
        float acc = 0.f;
        #pragma unroll
        for (int u = 0; u < 6; ++u) {
            v4f qv = qp[u], kv = kp[u];
            acc = __builtin_amdgcn_fdot2(__builtin_bit_cast(h2t, qv.x),
                    __builtin_bit_cast(h2t, kv.x), acc, false);
            acc = __builtin_amdgcn_fdot2(__builtin_bit_cast(h2t, qv.y),
                    __builtin_bit_cast(h2t, kv.y), acc, false);
            acc = __builtin_amdgcn_fdot2(__builtin_bit_cast(h2t, qv.z),
                    __builtin_bit_cast(h2t, kv.z), acc, false);
            acc = __builtin_amdgcn_fdot2(__builtin_bit_cast(h2t, qv.w),
                    __builtin_bit_cast(h2t, kv.w), acc, false);
        }
        ss[i * SSS + jj] = acc * 0.125f;
    }
    __syncthreads();

    // ---- row softmax (row in registers; R14-validated) ----
    if (tid < BATCH) {
        v4f* rp = (v4f*)&ss[tid * SSS];
        v4f r[10];
        #pragma unroll
        for (int u = 0; u < 10; ++u) r[u] = rp[u];
        float m = -1e30f;
        #pragma unroll
        for (int u = 0; u < 10; ++u)
            m = fmaxf(m, fmaxf(fmaxf(r[u].x, r[u].y), fmaxf(r[u].z, r[u].w)));
        float s = 0.f;
        #pragma unroll
        for (int u = 0; u < 10; ++u) {
            r[u].x = __expf(r[u].x - m); s += r[u].x;
            r[u].y = __expf(r[u].y - m); s += r[u].y;
            r[u].z = __expf(r[u].z - m); s += r[u].z;
            r[u].w = __expf(r[u].w - m); s += r[u].w;
        }
        float inv = __builtin_amdgcn_rcpf(s);
        #pragma unroll
        for (int u = 0; u < 10; ++u) {
            r[u].x *= inv; r[u].y *= inv; r[u].z *= inv; r[u].w *= inv;
            rp[u] = r[u];
        }
    }
    __syncthreads();

    // ---- AV: slot = (bi, 8 d's); 240 slots (R14-validated) ----
    if (tid < 240) {
        int bi = tid / 6, dg = tid % 6, d0 = dg * 8;
        const v4f* sp = (const v4f*)&ss[bi * SSS];
        v4f sr[10];
        #pragma unroll
        for (int u = 0; u < 10; ++u) sr[u] = sp[u];
        float acc[8];
        #pragma unroll
        for (int d = 0; d < 8; ++d) acc[d] = 0.f;
        for (int jj = 0; jj < 40; ++jj) {
            float a = ((const float*)&sr[jj >> 2])[jj & 3];
            v4f vv = *(const v4f*)&skqv[jj * SKVS + 96 + d0];  // v @ 96 (192B)
            #pragma unroll
            for (int w = 0; w < 4; ++w) {
                h2t pr = __builtin_bit_cast(h2t, ((const float*)&vv)[w]);
                acc[2 * w]     += a * (float)pr[0];
                acc[2 * w + 1] += a * (float)pr[1];
            }
        }
        float* ob = &o_buf[((size_t)t * BATCH + bi) * EMB + h * DH + d0];
        *(v4f*)&ob[0] = (v4f){acc[0], acc[1], acc[2], acc[3]};
        *(v4f*)&ob[4] = (v4f){acc[4], acc[5], acc[6], acc[7]};
    }
}

// ---------------------------------------------------------------------------
// Kernel 4: GLU + residual + LayerNorm, per t — R13-PROVEN VERBATIM.
// grid: 640 blocks, 256 threads.
// ---------------------------------------------------------------------------
__global__ void __launch_bounds__(256) k_glu_ln(
    const float* __restrict__ seq, const float* __restrict__ obuf,
    const float* __restrict__ Wa, const float* __restrict__ ba,
    const float* __restrict__ Wg, const float* __restrict__ bg,
    const float* __restrict__ gamma, const float* __restrict__ beta,
    float* __restrict__ out)
{
    const int t = blockIdx.x, tid = threadIdx.x;
    __shared__ float so[BATCH * 193];       // o_t padded (192 -> 193)
    __shared__ float sy[BATCH * 65];        // y padded
    __shared__ float sseq[BATCH * D_LSTM];

    const float* ot = obuf + (size_t)t * BATCH * EMB;
    for (int i = tid; i < BATCH * EMB; i += 256)
        so[(i / EMB) * 193 + (i % EMB)] = ot[i];
    for (int i = tid; i < BATCH * D_LSTM; i += 256)
        sseq[i] = seq[(size_t)t * BATCH * D_LSTM + i];
    __syncthreads();

    const int j = tid >> 2, bgr = tid & 3;
    float acc_a[10], acc_g[10];
    #pragma unroll
    for (int bb = 0; bb < 10; ++bb) { acc_a[bb] = ba[j]; acc_g[bb] = bg[j]; }

    const float* wa = Wa + j * EMB;
    const float* wg = Wg + j * EMB;
    for (int p = 0; p < EMB; ++p) {
        float a = wa[p], g = wg[p];
        #pragma unroll
        for (int bb = 0; bb < 10; ++bb) {
            float o = so[(bgr + 4 * bb) * 193 + p];
            acc_a[bb] += o * a;
            acc_g[bb] += o * g;
        }
    }
    #pragma unroll
    for (int bb = 0; bb < 10; ++bb) {
        int b = bgr + 4 * bb;
        float tv = acc_a[bb] * sigmoid_f(acc_g[bb]);
        sy[b * 65 + j] = sseq[b * D_LSTM + j] + tv;
    }
    __syncthreads();

    const int w = tid >> 6, lane = tid & 63;
    const float gm = gamma[lane], bt = beta[lane];
    for (int rr = 0; rr < 10; ++rr) {
        int b = w + 4 * rr;
        float y = sy[b * 65 + lane];
        float s1 = y, s2 = y * y;
        #pragma unroll
        for (int m = 1; m < 64; m <<= 1) {
            s1 += __shfl_xor(s1, m, 64);
            s2 += __shfl_xor(s2, m, 64);
        }
        float mu  = s1 * (1.f / 64.f);
        float var = s2 * (1.f / 64.f) - mu * mu;
        float inv = rsqrtf(var + 1e-5f);
        out[(size_t)t * BATCH * D_LSTM + b * D_LSTM + lane] =
            (y - mu) * inv * gm + bt;
    }
}

// ---------------------------------------------------------------------------
extern "C" void kernel_launch(void* const* d_in, const int* in_sizes, int n_in,
                              void* d_out, int out_size, void* d_ws, size_t ws_size,
                              hipStream_t stream)
{
    const float* hist = (const float*)d_in[0];
    // d_in[1] adj: unused (use_spatial=False)
    const float* W1   = (const float*)d_in[2];
    const float* b1   = (const float*)d_in[3];
    const float* W_ih = (const float*)d_in[4];
    const float* W_hh = (const float*)d_in[5];
    const float* b_ih = (const float*)d_in[6];
    const float* b_hh = (const float*)d_in[7];
    const float* Wq   = (const float*)d_in[8];
    const float* bq   = (const float*)d_in[9];
    const float* Wk   = (const float*)d_in[10];
    const float* bk   = (const float*)d_in[11];
    const float* Wv   = (const float*)d_in[12];
    const float* bv   = (const float*)d_in[13];
    const float* Wa   = (const float*)d_in[14];
    const float* ba   = (const float*)d_in[15];
    const float* Wg   = (const float*)d_in[16];
    const float* bg   = (const float*)d_in[17];
    const float* gamma = (const float*)d_in[18];
    const float* beta  = (const float*)d_in[19];
    float* out = (float*)d_out;

    float* ws = (float*)d_ws;
    float* gates_x = ws;                                   // 640*40*256 f
    float* seq     = ws + 6553600;                         // 640*40*64 f
    float* obuf    = ws + 6553600 + 1638400;               // 640*40*192 f

    hipLaunchKernelGGL(k_embed, dim3(SEQ), dim3(256), 0, stream,
                       hist, W1, b1, W_ih, b_ih, b_hh, gates_x);
    hipLaunchKernelGGL(k_lstm, dim3(BATCH), dim3(256), 0, stream,
                       gates_x, W_hh, seq);
    hipLaunchKernelGGL(k_attn, dim3(NH, SEQ), dim3(256), 0, stream,
                       seq, Wq, bq, Wk, bk, Wv, bv, obuf);
    hipLaunchKernelGGL(k_glu_ln, dim3(SEQ), dim3(256), 0, stream,
                       seq, obuf, Wa, ba, Wg, bg, gamma, beta, out);
}

// Round 8
// 458.705 us; speedup vs baseline: 1.0211x; 1.0205x over previous
//
#include <hip/hip_runtime.h>

#define SEQ 640
#define BATCH 40
#define D_IN 8
#define D_TRAJ 32
#define D_LSTM 64
#define G4 256        // 4 * D_LSTM
#define NH 4
#define DH 48
#define EMB 192

typedef float v2f __attribute__((ext_vector_type(2)));
typedef float v4f __attribute__((ext_vector_type(4)));
typedef _Float16 h2t __attribute__((ext_vector_type(2)));

__device__ __forceinline__ float sigmoid_f(float x) {
    float e = __expf(-x);
    return __builtin_amdgcn_rcpf(1.f + e);
}
__device__ __forceinline__ float tanh_f(float x) {
    float e = __expf(2.f * x);
    return 1.f - 2.f * __builtin_amdgcn_rcpf(e + 1.f);
}

// ---------------------------------------------------------------------------
// Kernel 1: trajectory embed (ELU) + input-side LSTM gate precompute.
// gates_x layout [b][g][t][j] (R1-proven). Single change vs R1: the b-loop
// reads sh_traj as v4f (b128) instead of 32 scalar b32 — 4x fewer LDS ops,
// same-element float<->v4f punning (session-proven), sequential component
// adds keep the FP order bit-identical.
// grid: 640 blocks (t), 256 threads.
// ---------------------------------------------------------------------------
__global__ void __launch_bounds__(256) k_embed(
    const float* __restrict__ hist, const float* __restrict__ W1,
    const float* __restrict__ b1, const float* __restrict__ W_ih,
    const float* __restrict__ b_ih, const float* __restrict__ b_hh,
    float* __restrict__ gates_x)
{
    __shared__ float sh_hist[BATCH * D_IN];                   // 320
    __shared__ __align__(16) float sh_traj[BATCH * D_TRAJ];   // 1280
    const int t = blockIdx.x, tid = threadIdx.x;

    for (int i = tid; i < BATCH * D_IN; i += 256)
        sh_hist[i] = hist[t * BATCH * D_IN + i];
    __syncthreads();

    for (int idx = tid; idx < BATCH * D_TRAJ; idx += 256) {
        int b = idx >> 5, h = idx & 31;
        float acc = b1[h];
        #pragma unroll
        for (int f = 0; f < D_IN; ++f)
            acc += sh_hist[b * D_IN + f] * W1[h * D_IN + f];
        sh_traj[idx] = acc > 0.f ? acc : (__expf(acc) - 1.f);   // ELU
    }
    __syncthreads();

    float w[D_TRAJ];
    {
        const v4f* wv = (const v4f*)(W_ih + tid * D_TRAJ);
        #pragma unroll
        for (int u = 0; u < 8; ++u) {
            v4f x = wv[u];
            w[4*u] = x.x; w[4*u+1] = x.y; w[4*u+2] = x.z; w[4*u+3] = x.w;
        }
    }
    const float bias = b_ih[tid] + b_hh[tid];
    const int j = tid & 63, g = tid >> 6;       // unit, gate-type

    for (int b = 0; b < BATCH; ++b) {
        const v4f* tp = (const v4f*)&sh_traj[b * D_TRAJ];  // 128B-aligned rows
        float acc = bias;
        #pragma unroll
        for (int u = 0; u < 8; ++u) {
            v4f tv = tp[u];
            acc += tv.x * w[4*u];      // sequential adds: same FP order as
            acc += tv.y * w[4*u+1];    // the scalar loop (bit-identical)
            acc += tv.z * w[4*u+2];
            acc += tv.w * w[4*u+3];
        }
        // [b][g][t][j] — coalesced per-wave per-step read in k_lstm
        gates_x[(((size_t)b * 4 + g) * SEQ + t) * 64 + j] = acc;
    }
}

// ---------------------------------------------------------------------------
// Kernel 2: LSTM recurrence — R1-EXACT (measured 230.5 us, absmax 0.015625).
// R4/R5/R6 post-mortem: every variant replacing the readlane broadcast with
// a packed-f16 LDS buffer failed bit-identically (absmax 2.121094) -> the
// mixed-element-type LDS punning (f16 stores / v4f float loads) on the
// loop-carried h path is broken on this toolchain and is BANNED. Reverted.
// grid: 40 blocks x 256 threads.
// ---------------------------------------------------------------------------
__global__ void __launch_bounds__(256, 1) k_lstm(
    const float* __restrict__ gates_x, const float* __restrict__ W_hh,
    float* __restrict__ seq_out)
{
    const int b = blockIdx.x;
    const int tid = threadIdx.x;
    const int g = tid >> 6;      // wave id == gate (i, f, g, o)
    const int j = tid & 63;      // unit

    __shared__ float sg[2][4][64];   // double-buffered raw gate sums

    // f16-packed recurrent weight row for (gate g, unit j)
    h2t w2[32];
    {
        const float* Wrow = W_hh + (g * 64 + j) * D_LSTM;
        #pragma unroll
        for (int m = 0; m < 32; ++m)
            w2[m] = (h2t){(_Float16)Wrow[2*m], (_Float16)Wrow[2*m+1]};
    }

    // x-side gate stream: [b][g][t][j], one dword per lane per step
    const float* gx = gates_x + (((size_t)b * 4 + g) * SEQ) * 64 + j;
    float gq0 = gx[0 * 64];
    float gq1 = gx[1 * 64];
    float gq2 = gx[2 * 64];
    float gq3 = gx[3 * 64];

    float h = 0.f, c = 0.f;
    float hpf = 0.f;                 // packed f16 pair (h_{2m}, h_{2m+1})
    const bool odd = (j & 1);

    auto step = [&](float& gq, int t) {
        const int hbits = __builtin_bit_cast(int, hpf);

        // gate-g matvec: 4 independent chains of 8 fdot2
        float a0 = gq, a1 = 0.f, a2 = 0.f, a3 = 0.f;
        #pragma unroll
        for (int m = 0; m < 8; ++m) {
            h2t p = __builtin_bit_cast(h2t, __builtin_amdgcn_readlane(hbits, 2*m));
            a0 = __builtin_amdgcn_fdot2(w2[m], p, a0, false);
        }
        #pragma unroll
        for (int m = 8; m < 16; ++m) {
            h2t p = __builtin_bit_cast(h2t, __builtin_amdgcn_readlane(hbits, 2*m));
            a1 = __builtin_amdgcn_fdot2(w2[m], p, a1, false);
        }
        #pragma unroll
        for (int m = 16; m < 24; ++m) {
            h2t p = __builtin_bit_cast(h2t, __builtin_amdgcn_readlane(hbits, 2*m));
            a2 = __builtin_amdgcn_fdot2(w2[m], p, a2, false);
        }
        #pragma unroll
        for (int m = 24; m < 32; ++m) {
            h2t p = __builtin_bit_cast(h2t, __builtin_amdgcn_readlane(hbits, 2*m));
            a3 = __builtin_amdgcn_fdot2(w2[m], p, a3, false);
        }
        float a = (a0 + a1) + (a2 + a3);

        // exchange gates (conflict-free: wave g writes contiguous row g)
        const int buf = t & 1;
        sg[buf][g][j] = a;
        __syncthreads();
        float ai = sg[buf][0][j];
        float af = sg[buf][1][j];
        float ag = sg[buf][2][j];
        float ao = sg[buf][3][j];

        // redundant identical (c,h) update in every wave
        c = sigmoid_f(af) * c + sigmoid_f(ai) * tanh_f(ag);
        h = sigmoid_f(ao) * tanh_f(c);
        if (g == 0)
            seq_out[(size_t)(t * BATCH + b) * D_LSTM + j] = h;

        // pack (h_2m, h_2m+1) as f16 pair for next step's readlane broadcast
        int own = (int)__builtin_bit_cast(unsigned short, (_Float16)h);
        int nb  = __builtin_amdgcn_update_dpp(0, own, 0xB1, 0xF, 0xF, true);
        int pk  = odd ? (nb | (own << 16)) : (own | (nb << 16));
        hpf = __builtin_bit_cast(float, pk);

        // prefetch x-gate 4 steps ahead
        int tp = t + 4; if (tp > SEQ - 1) tp = SEQ - 1;
        gq = gx[(size_t)tp * 64];
    };

    for (int t = 0; t < SEQ; t += 4) {
        step(gq0, t + 0);
        step(gq1, t + 1);
        step(gq2, t + 2);
        step(gq3, t + 3);
    }
}

// ---------------------------------------------------------------------------
// Kernel 3: attention, per-(head, t) — UNCHANGED (R14/R17-proven).
// grid: dim3(NH, SEQ), 256 threads.
// ---------------------------------------------------------------------------
#define SAS 68     // f32 stride of sA rows (16B-aligned)
#define SKVS 152   // f16 stride of qkv rows (304B, 16B-aligned): q@0,k@48,v@96
#define SSS 44     // f32 stride for score rows
__global__ void __launch_bounds__(256) k_attn(
    const float* __restrict__ seq,
    const float* __restrict__ Wq, const float* __restrict__ bq,
    const float* __restrict__ Wk, const float* __restrict__ bk,
    const float* __restrict__ Wv, const float* __restrict__ bv,
    float* __restrict__ o_buf)
{
    const int h = blockIdx.x, t = blockIdx.y, tid = threadIdx.x;
    __shared__ float sA[BATCH * SAS];          // 10.9 KB (f32)
    __shared__ _Float16 skqv[BATCH * SKVS];    // 12.2 KB
    __shared__ float ss[BATCH * SSS];          // 7.0 KB

    // ---- stage seq_t as f32 ----
    for (int i = tid; i < BATCH * D_LSTM; i += 256)
        sA[(i >> 6) * SAS + (i & 63)] = seq[(size_t)t * BATCH * D_LSTM + i];
    __syncthreads();

    // ---- projection: thread c (<144) owns one channel; f32 math ----
    if (tid < 144) {
        int m = tid / 48, d = tid - m * 48;
        const float* W = (m == 0) ? Wq : (m == 1) ? Wk : Wv;
        const float* B = (m == 0) ? bq : (m == 1) ? bk : bv;
        const float* wrow = W + (h * DH + d) * D_LSTM;
        float wreg[D_LSTM];
        {
            const v4f* wv = (const v4f*)wrow;   // coalesced f32 loads
            #pragma unroll
            for (int u = 0; u < 16; ++u) {
                v4f x = wv[u];
                wreg[4*u] = x.x; wreg[4*u+1] = x.y;
                wreg[4*u+2] = x.z; wreg[4*u+3] = x.w;
            }
        }
        const float bias = B[h * DH + d];

        for (int a = 0; a < BATCH; ++a) {
            const v4f* ap = (const v4f*)&sA[a * SAS];   // broadcast b128 reads
            float acc = bias;
            #pragma unroll
            for (int u = 0; u < 16; ++u) {
                v4f av = ap[u];
                acc += av.x * wreg[4*u]   + av.y * wreg[4*u+1]
                     + av.z * wreg[4*u+2] + av.w * wreg[4*u+3];
            }
            skqv[a * SKVS + tid] = (_Float16)acc;       // f16 store (proven)
        }
    }
    __syncthreads();

    // ---- scores = q k^T / 8 (f16 dots, R14-proven) ----
    for (int idx = tid; idx < BATCH * BATCH; idx += 256) {
        int i = idx / BATCH, jj = idx % BATCH;
        const v4f* qp = (const v4f*)&skqv[i * SKVS];        // q @ 0
        const v4f* kp = (const v4f*)&skqv[jj * SKVS + 48];  // k @ 48 (96B)
        float acc = 0.f;
        #pragma unroll
        for (int u = 0; u < 6; ++u) {
            v4f qv = qp[u], kv = kp[u];
            acc = __builtin_amdgcn_fdot2(__builtin_bit_cast(h2t, qv.x),
                    __builtin_bit_cast(h2t, kv.x), acc, false);
            acc = __builtin_amdgcn_fdot2(__builtin_bit_cast(h2t, qv.y),
                    __builtin_bit_cast(h2t, kv.y), acc, false);
            acc = __builtin_amdgcn_fdot2(__builtin_bit_cast(h2t, qv.z),
                    __builtin_bit_cast(h2t, kv.z), acc, false);
            acc = __builtin_amdgcn_fdot2(__builtin_bit_cast(h2t, qv.w),
                    __builtin_bit_cast(h2t, kv.w), acc, false);
        }
        ss[i * SSS + jj] = acc * 0.125f;
    }
    __syncthreads();

    // ---- row softmax (row in registers; R14-validated) ----
    if (tid < BATCH) {
        v4f* rp = (v4f*)&ss[tid * SSS];
        v4f r[10];
        #pragma unroll
        for (int u = 0; u < 10; ++u) r[u] = rp[u];
        float m = -1e30f;
        #pragma unroll
        for (int u = 0; u < 10; ++u)
            m = fmaxf(m, fmaxf(fmaxf(r[u].x, r[u].y), fmaxf(r[u].z, r[u].w)));
        float s = 0.f;
        #pragma unroll
        for (int u = 0; u < 10; ++u) {
            r[u].x = __expf(r[u].x - m); s += r[u].x;
            r[u].y = __expf(r[u].y - m); s += r[u].y;
            r[u].z = __expf(r[u].z - m); s += r[u].z;
            r[u].w = __expf(r[u].w - m); s += r[u].w;
        }
        float inv = __builtin_amdgcn_rcpf(s);
        #pragma unroll
        for (int u = 0; u < 10; ++u) {
            r[u].x *= inv; r[u].y *= inv; r[u].z *= inv; r[u].w *= inv;
            rp[u] = r[u];
        }
    }
    __syncthreads();

    // ---- AV: slot = (bi, 8 d's); 240 slots (R14-validated) ----
    if (tid < 240) {
        int bi = tid / 6, dg = tid % 6, d0 = dg * 8;
        const v4f* sp = (const v4f*)&ss[bi * SSS];
        v4f sr[10];
        #pragma unroll
        for (int u = 0; u < 10; ++u) sr[u] = sp[u];
        float acc[8];
        #pragma unroll
        for (int d = 0; d < 8; ++d) acc[d] = 0.f;
        for (int jj = 0; jj < 40; ++jj) {
            float a = ((const float*)&sr[jj >> 2])[jj & 3];
            v4f vv = *(const v4f*)&skqv[jj * SKVS + 96 + d0];  // v @ 96 (192B)
            #pragma unroll
            for (int w = 0; w < 4; ++w) {
                h2t pr = __builtin_bit_cast(h2t, ((const float*)&vv)[w]);
                acc[2 * w]     += a * (float)pr[0];
                acc[2 * w + 1] += a * (float)pr[1];
            }
        }
        float* ob = &o_buf[((size_t)t * BATCH + bi) * EMB + h * DH + d0];
        *(v4f*)&ob[0] = (v4f){acc[0], acc[1], acc[2], acc[3]};
        *(v4f*)&ob[4] = (v4f){acc[4], acc[5], acc[6], acc[7]};
    }
}

// ---------------------------------------------------------------------------
// Kernel 4: GLU + residual + LayerNorm, per t — R13 base, p-loop VECTORIZED:
// so padded 193 -> 196 (784B rows, 16B-aligned, conflict-free: bgr rows hit
// banks {x, x+4, x+8, x+12}); wa/wg/so read as v4f (480 b128 LDS reads vs
// 1920 scalar b32). Per-accumulator add order unchanged -> bit-identical.
// grid: 640 blocks, 256 threads.
// ---------------------------------------------------------------------------
__global__ void __launch_bounds__(256) k_glu_ln(
    const float* __restrict__ seq, const float* __restrict__ obuf,
    const float* __restrict__ Wa, const float* __restrict__ ba,
    const float* __restrict__ Wg, const float* __restrict__ bg,
    const float* __restrict__ gamma, const float* __restrict__ beta,
    float* __restrict__ out)
{
    const int t = blockIdx.x, tid = threadIdx.x;
    __shared__ __align__(16) float so[BATCH * 196];   // o_t padded (16B rows)
    __shared__ float sy[BATCH * 65];                  // y padded
    __shared__ float sseq[BATCH * D_LSTM];

    const float* ot = obuf + (size_t)t * BATCH * EMB;
    for (int i = tid; i < BATCH * EMB; i += 256)
        so[(i / EMB) * 196 + (i % EMB)] = ot[i];
    for (int i = tid; i < BATCH * D_LSTM; i += 256)
        sseq[i] = seq[(size_t)t * BATCH * D_LSTM + i];
    __syncthreads();

    const int j = tid >> 2, bgr = tid & 3;
    float acc_a[10], acc_g[10];
    #pragma unroll
    for (int bb = 0; bb < 10; ++bb) { acc_a[bb] = ba[j]; acc_g[bb] = bg[j]; }

    const v4f* wav = (const v4f*)(Wa + j * EMB);   // 768B rows, 16B-aligned
    const v4f* wgv = (const v4f*)(Wg + j * EMB);
    for (int p4 = 0; p4 < EMB / 4; ++p4) {
        v4f av = wav[p4], gv = wgv[p4];
        #pragma unroll
        for (int bb = 0; bb < 10; ++bb) {
            v4f ov = *(const v4f*)&so[(bgr + 4 * bb) * 196 + 4 * p4];
            acc_a[bb] += ov.x * av.x;   // sequential adds: same per-acc
            acc_a[bb] += ov.y * av.y;   // FP order as the scalar loop
            acc_a[bb] += ov.z * av.z;
            acc_a[bb] += ov.w * av.w;
            acc_g[bb] += ov.x * gv.x;
            acc_g[bb] += ov.y * gv.y;
            acc_g[bb] += ov.z * gv.z;
            acc_g[bb] += ov.w * gv.w;
        }
    }
    #pragma unroll
    for (int bb = 0; bb < 10; ++bb) {
        int b = bgr + 4 * bb;
        float tv = acc_a[bb] * sigmoid_f(acc_g[bb]);
        sy[b * 65 + j] = sseq[b * D_LSTM + j] + tv;
    }
    __syncthreads();

    const int w = tid >> 6, lane = tid & 63;
    const float gm = gamma[lane], bt = beta[lane];
    for (int rr = 0; rr < 10; ++rr) {
        int b = w + 4 * rr;
        float y = sy[b * 65 + lane];
        float s1 = y, s2 = y * y;
        #pragma unroll
        for (int m = 1; m < 64; m <<= 1) {
            s1 += __shfl_xor(s1, m, 64);
            s2 += __shfl_xor(s2, m, 64);
        }
        float mu  = s1 * (1.f / 64.f);
        float var = s2 * (1.f / 64.f) - mu * mu;
        float inv = rsqrtf(var + 1e-5f);
        out[(size_t)t * BATCH * D_LSTM + b * D_LSTM + lane] =
            (y - mu) * inv * gm + bt;
    }
}

// ---------------------------------------------------------------------------
extern "C" void kernel_launch(void* const* d_in, const int* in_sizes, int n_in,
                              void* d_out, int out_size, void* d_ws, size_t ws_size,
                              hipStream_t stream)
{
    const float* hist = (const float*)d_in[0];
    // d_in[1] adj: unused (use_spatial=False)
    const float* W1   = (const float*)d_in[2];
    const float* b1   = (const float*)d_in[3];
    const float* W_ih = (const float*)d_in[4];
    const float* W_hh = (const float*)d_in[5];
    const float* b_ih = (const float*)d_in[6];
    const float* b_hh = (const float*)d_in[7];
    const float* Wq   = (const float*)d_in[8];
    const float* bq   = (const float*)d_in[9];
    const float* Wk   = (const float*)d_in[10];
    const float* bk   = (const float*)d_in[11];
    const float* Wv   = (const float*)d_in[12];
    const float* bv   = (const float*)d_in[13];
    const float* Wa   = (const float*)d_in[14];
    const float* ba   = (const float*)d_in[15];
    const float* Wg   = (const float*)d_in[16];
    const float* bg   = (const float*)d_in[17];
    const float* gamma = (const float*)d_in[18];
    const float* beta  = (const float*)d_in[19];
    float* out = (float*)d_out;

    float* ws = (float*)d_ws;
    float* gates_x = ws;                                   // 640*40*256 f
    float* seq     = ws + 6553600;                         // 640*40*64 f
    float* obuf    = ws + 6553600 + 1638400;               // 640*40*192 f

    hipLaunchKernelGGL(k_embed, dim3(SEQ), dim3(256), 0, stream,
                       hist, W1, b1, W_ih, b_ih, b_hh, gates_x);
    hipLaunchKernelGGL(k_lstm, dim3(BATCH), dim3(256), 0, stream,
                       gates_x, W_hh, seq);
    hipLaunchKernelGGL(k_attn, dim3(NH, SEQ), dim3(256), 0, stream,
                       seq, Wq, bq, Wk, bk, Wv, bv, obuf);
    hipLaunchKernelGGL(k_glu_ln, dim3(SEQ), dim3(256), 0, stream,
                       seq, obuf, Wa, ba, Wg, bg, gamma, beta, out);
}